// Round 3
// baseline (99.632 us; speedup 1.0000x reference)
//
#include <hip/hip_runtime.h>
#include <stdint.h>

// ---------------------------------------------------------------------------
// AdditiveAttention (Bahdanau) + gumbel-softmax(tau=0.01), channel 0.
//
// out[b,i,j] = sigmoid( ((s0+g0) - (masked1+g1)) * 100 )
//   s_c       = sum_h tanh(q[b,i,h] + k[b,j,h]) * Wv[c,h]
//   masked1   = s1 if mask==2 else -1e6   (channel 0 never masked, mask>=1)
//   g         = jax.random.gumbel(jax.random.key(42), (B,Lq,Lk,2), f32)
//
// RNG_VARIANT: exact replication of jax threefry random_bits.
//   1 = partitionable (jax >= 0.4.30 default): block (hi=0, lo=flat), o0^o1
//   2 = partitionable, take o0
//   3 = legacy split-iota mode (jax_threefry_partitionable=False)
// ---------------------------------------------------------------------------

#define RNG_VARIANT 1

#define BB 4
#define LLEN 512
#define DD 256
#define HH 128

__device__ __forceinline__ uint32_t rotl32(uint32_t v, int r) {
  return (v << r) | (v >> (32 - r));
}

// Threefry-2x32, key = (0, 42)  [jax.random.key(42) -> (hi,lo)=(0,42)]
__device__ __forceinline__ void tf2x32(uint32_t x0, uint32_t x1,
                                       uint32_t& o0, uint32_t& o1) {
  const uint32_t k0 = 0u;
  const uint32_t k1 = 42u;
  const uint32_t k2 = 0x1BD11BDAu ^ k0 ^ k1;  // 0x1BD11BF0

  x0 += k0; x1 += k1;
#define TFR(r) { x0 += x1; x1 = rotl32(x1, (r)); x1 ^= x0; }
  TFR(13) TFR(15) TFR(26) TFR(6)
  x0 += k1; x1 += k2 + 1u;
  TFR(17) TFR(29) TFR(16) TFR(24)
  x0 += k2; x1 += k0 + 2u;
  TFR(13) TFR(15) TFR(26) TFR(6)
  x0 += k0; x1 += k1 + 3u;
  TFR(17) TFR(29) TFR(16) TFR(24)
  x0 += k1; x1 += k2 + 4u;
  TFR(13) TFR(15) TFR(26) TFR(6)
  x0 += k2; x1 += k0 + 5u;
#undef TFR
  o0 = x0; o1 = x1;
}

__device__ __forceinline__ uint32_t jax_random_bits32(uint32_t flat) {
#if RNG_VARIANT == 1
  uint32_t o0, o1;
  tf2x32(0u, flat, o0, o1);     // counter u64: hi=0 (x0), lo=flat (x1)
  return o0 ^ o1;
#elif RNG_VARIANT == 2
  uint32_t o0, o1;
  tf2x32(0u, flat, o0, o1);
  return o0;
#else
  // legacy: bits = threefry(key, iota(2N)) with iota split in halves
  const uint32_t N = (BB * LLEN * LLEN * 2) / 2;  // 1048576
  uint32_t o0, o1;
  if (flat < N) { tf2x32(flat, flat + N, o0, o1); return o0; }
  else          { tf2x32(flat - N, flat, o0, o1); return o1; }
#endif
}

// jax: u = max(tiny, ((bits>>9)|0x3f800000) - 1.0); g = -log(-log(u))
// NOTE: libm logf (not __logf) — need full relative accuracy for u near 1.
__device__ __forceinline__ float jax_gumbel(uint32_t flat) {
  const uint32_t bits = jax_random_bits32(flat);
  const float f = __uint_as_float((bits >> 9) | 0x3F800000u) - 1.0f;
  const float u = fmaxf(f, 1.17549435e-38f);
  const float L = -logf(u);
  return -logf(L);
}

// tanh via hw exp; abs error ~1e-7, fine for the error budget.
__device__ __forceinline__ float fast_tanh(float x) {
  const float xc = fminf(fmaxf(x, -15.0f), 15.0f);
  const float e = __expf(2.0f * xc);
  return 1.0f - __fdividef(2.0f, e + 1.0f);
}

// ---------------------------------------------------------------------------
// Kernel A: projections.  blocks 0..511 -> Q rows, 512..1023 -> K rows.
// Each block: 4 rows of input staged in LDS; thread h does 256-long dots.
// ---------------------------------------------------------------------------
__global__ __launch_bounds__(128) void proj_kernel(
    const float* __restrict__ queries, const float* __restrict__ keys,
    const float* __restrict__ Wq, const float* __restrict__ Wk,
    float* __restrict__ Qp, float* __restrict__ Kp) {
  const int blk = blockIdx.x;
  const bool isK = blk >= (BB * LLEN / 4);
  const int rb = (isK ? blk - (BB * LLEN / 4) : blk) * 4;  // row base (of 2048)
  const float* __restrict__ in  = isK ? keys : queries;
  const float* __restrict__ W   = isK ? Wk : Wq;
  float* __restrict__ outp      = isK ? Kp : Qp;

  __shared__ float rows[4][DD];
  const float4* in4 = reinterpret_cast<const float4*>(in + (size_t)rb * DD);
  float4* rows4 = reinterpret_cast<float4*>(&rows[0][0]);
  for (int t = threadIdx.x; t < 4 * DD / 4; t += 128) rows4[t] = in4[t];
  __syncthreads();

  const int h = threadIdx.x;
  const float4* W4 = reinterpret_cast<const float4*>(W + (size_t)h * DD);
  float a0 = 0.f, a1 = 0.f, a2 = 0.f, a3 = 0.f;
  #pragma unroll 4
  for (int d4 = 0; d4 < DD / 4; ++d4) {
    const float4 w = W4[d4];
    const int d = d4 * 4;
    a0 = fmaf(w.x, rows[0][d], fmaf(w.y, rows[0][d+1], fmaf(w.z, rows[0][d+2], fmaf(w.w, rows[0][d+3], a0))));
    a1 = fmaf(w.x, rows[1][d], fmaf(w.y, rows[1][d+1], fmaf(w.z, rows[1][d+2], fmaf(w.w, rows[1][d+3], a1))));
    a2 = fmaf(w.x, rows[2][d], fmaf(w.y, rows[2][d+1], fmaf(w.z, rows[2][d+2], fmaf(w.w, rows[2][d+3], a2))));
    a3 = fmaf(w.x, rows[3][d], fmaf(w.y, rows[3][d+1], fmaf(w.z, rows[3][d+2], fmaf(w.w, rows[3][d+3], a3))));
  }
  float* orow = outp + (size_t)rb * HH + h;
  orow[0 * HH] = a0; orow[1 * HH] = a1; orow[2 * HH] = a2; orow[3 * HH] = a3;
}

// ---------------------------------------------------------------------------
// Kernel B: 32x32 output tile per block (grid 16x16x4), 256 threads,
// 4 outputs/thread.  Q/K tiles in LDS as float4 with odd stride 33
// (conflict-free ds_read_b128: 8 consecutive lanes fill all 32 banks).
// ---------------------------------------------------------------------------
__global__ __launch_bounds__(256) void attn_kernel(
    const float* __restrict__ Qp, const float* __restrict__ Kp,
    const int* __restrict__ mask, const float* __restrict__ Wv,
    float* __restrict__ out) {
  __shared__ float4 QL[32][33];
  __shared__ float4 KL[32][33];
  __shared__ float4 WvL[64];  // [0..31]=Wv[0][h], [32..63]=Wv[1][h]

  const int bi = blockIdx.x, bj = blockIdx.y, b = blockIdx.z;
  const int i0 = bi * 32, j0 = bj * 32;

  const float4* Q4 = reinterpret_cast<const float4*>(Qp) + ((size_t)b * LLEN + i0) * (HH / 4);
  const float4* K4 = reinterpret_cast<const float4*>(Kp) + ((size_t)b * LLEN + j0) * (HH / 4);
  for (int t = threadIdx.x; t < 32 * (HH / 4); t += 256) {
    QL[t >> 5][t & 31] = Q4[t];
    KL[t >> 5][t & 31] = K4[t];
  }
  if (threadIdx.x < 64)
    WvL[threadIdx.x] = reinterpret_cast<const float4*>(Wv)[threadIdx.x];
  __syncthreads();

  const int jj = threadIdx.x & 31;   // j within tile
  const int ib = threadIdx.x >> 5;   // i base (0..7); rows ib, ib+8, ib+16, ib+24

  float s0[4] = {0.f, 0.f, 0.f, 0.f};
  float s1[4] = {0.f, 0.f, 0.f, 0.f};

  #pragma unroll 4
  for (int h4 = 0; h4 < HH / 4; ++h4) {
    const float4 kv = KL[jj][h4];
    const float4 w0 = WvL[h4];
    const float4 w1 = WvL[32 + h4];
    #pragma unroll
    for (int r = 0; r < 4; ++r) {
      const float4 qv = QL[ib + 8 * r][h4];
      const float t0 = fast_tanh(qv.x + kv.x);
      const float t1 = fast_tanh(qv.y + kv.y);
      const float t2 = fast_tanh(qv.z + kv.z);
      const float t3 = fast_tanh(qv.w + kv.w);
      s0[r] = fmaf(t0, w0.x, fmaf(t1, w0.y, fmaf(t2, w0.z, fmaf(t3, w0.w, s0[r]))));
      s1[r] = fmaf(t0, w1.x, fmaf(t1, w1.y, fmaf(t2, w1.z, fmaf(t3, w1.w, s1[r]))));
    }
  }

  #pragma unroll
  for (int r = 0; r < 4; ++r) {
    const int i = i0 + ib + 8 * r;
    const int j = j0 + jj;
    const uint32_t idx = ((uint32_t)b * LLEN + i) * LLEN + j;
    const int m = mask[idx];
    const float g0 = jax_gumbel(idx * 2u);
    const float g1 = jax_gumbel(idx * 2u + 1u);
    const float a0 = s0[r] + g0;
    const float a1 = (m >= 2) ? (s1[r] + g1) : (-1000000.0f + g1);
    const float arg = (a0 - a1) * 100.0f;   // (x0 - x1)/tau
    out[idx] = 1.0f / (1.0f + __expf(-arg));  // softmax channel 0
  }
}

extern "C" void kernel_launch(void* const* d_in, const int* in_sizes, int n_in,
                              void* d_out, int out_size, void* d_ws, size_t ws_size,
                              hipStream_t stream) {
  const float* queries = (const float*)d_in[0];
  const float* keys    = (const float*)d_in[1];
  const int*   mask    = (const int*)d_in[2];
  const float* Wq      = (const float*)d_in[3];
  const float* Wk      = (const float*)d_in[4];
  const float* Wv      = (const float*)d_in[5];
  float* out = (float*)d_out;

  // workspace: Qp [2048][128] f32, Kp [2048][128] f32  (2 MB total)
  float* Qp = (float*)d_ws;
  float* Kp = Qp + (size_t)BB * LLEN * HH;

  proj_kernel<<<dim3(2 * (BB * LLEN / 4)), dim3(128), 0, stream>>>(
      queries, keys, Wq, Wk, Qp, Kp);
  attn_kernel<<<dim3(LLEN / 32, LLEN / 32, BB), dim3(256), 0, stream>>>(
      Qp, Kp, mask, Wv, out);
}

// Round 4
// 75.173 us; speedup vs baseline: 1.3254x; 1.3254x over previous
//
#include <hip/hip_runtime.h>
#include <stdint.h>

// ---------------------------------------------------------------------------
// AdditiveAttention (Bahdanau) + gumbel-softmax(tau=0.01), channel 0.
//
// out[b,i,j] = (mask==1) ? 1.0
//            : sigmoid( (d + g0 - g1) * 100 ),  d = sum_h tanh(q+k)*(w0-w1)
//
// g = jax.random.gumbel(key(42)) replicated bit-exactly (threefry-2x32,
// partitionable counter mode, o0^o1) — verified passing in R3.
//
// tanh via 288-segment linear-interp LDS LUT on [-4.5,4.5] (sat error 2.5e-4,
// interp error 9.4e-5). Proj kernel pre-scales: Qp=32q+72, Kp=32k+72 so the
// LUT coordinate is a single add: s = Qp+Kp = 32(q+k)+144 in [0,288].
// ---------------------------------------------------------------------------

#define BB 4
#define LLEN 512
#define DD 256
#define HH 128
#define NSEG 288   // segments over [-4.5, 4.5], spacing 1/32

__device__ __forceinline__ uint32_t rotl32(uint32_t v, int r) {
  return (v << r) | (v >> (32 - r));
}

// Threefry-2x32, key = (0, 42)
__device__ __forceinline__ void tf2x32(uint32_t x0, uint32_t x1,
                                       uint32_t& o0, uint32_t& o1) {
  const uint32_t k0 = 0u;
  const uint32_t k1 = 42u;
  const uint32_t k2 = 0x1BD11BDAu ^ k0 ^ k1;

  x0 += k0; x1 += k1;
#define TFR(r) { x0 += x1; x1 = rotl32(x1, (r)); x1 ^= x0; }
  TFR(13) TFR(15) TFR(26) TFR(6)
  x0 += k1; x1 += k2 + 1u;
  TFR(17) TFR(29) TFR(16) TFR(24)
  x0 += k2; x1 += k0 + 2u;
  TFR(13) TFR(15) TFR(26) TFR(6)
  x0 += k0; x1 += k1 + 3u;
  TFR(17) TFR(29) TFR(16) TFR(24)
  x0 += k1; x1 += k2 + 4u;
  TFR(13) TFR(15) TFR(26) TFR(6)
  x0 += k2; x1 += k0 + 5u;
#undef TFR
  o0 = x0; o1 = x1;
}

// jax partitionable random_bits: counter u64 = flat -> block (0, flat), o0^o1
// u = max(tiny, ((bits>>9)|0x3f800000) - 1); g = -log(-log(u)).
// v_log_f32 is ~1ulp; inner log's RELATIVE accuracy is what matters at u->1.
__device__ __forceinline__ float jax_gumbel(uint32_t flat) {
  uint32_t o0, o1;
  tf2x32(0u, flat, o0, o1);
  const uint32_t bits = o0 ^ o1;
  const float f = __uint_as_float((bits >> 9) | 0x3F800000u) - 1.0f;
  const float u = fmaxf(f, 1.17549435e-38f);
  const float L = -__logf(u);
  return -__logf(L);
}

// ---------------------------------------------------------------------------
// Kernel A: projections, pre-scaled for the LUT: out = 32*(in.W^T) + 72.
// blocks 0..511 -> Q rows, 512..1023 -> K rows; 4 rows/block, thread = h.
// ---------------------------------------------------------------------------
__global__ __launch_bounds__(128) void proj_kernel(
    const float* __restrict__ queries, const float* __restrict__ keys,
    const float* __restrict__ Wq, const float* __restrict__ Wk,
    float* __restrict__ Qp, float* __restrict__ Kp) {
  const int blk = blockIdx.x;
  const bool isK = blk >= (BB * LLEN / 4);
  const int rb = (isK ? blk - (BB * LLEN / 4) : blk) * 4;
  const float* __restrict__ in  = isK ? keys : queries;
  const float* __restrict__ W   = isK ? Wk : Wq;
  float* __restrict__ outp      = isK ? Kp : Qp;

  __shared__ float rows[4][DD];
  const float4* in4 = reinterpret_cast<const float4*>(in + (size_t)rb * DD);
  float4* rows4 = reinterpret_cast<float4*>(&rows[0][0]);
  for (int t = threadIdx.x; t < 4 * DD / 4; t += 128) rows4[t] = in4[t];
  __syncthreads();

  const int h = threadIdx.x;
  const float4* W4 = reinterpret_cast<const float4*>(W + (size_t)h * DD);
  float a0 = 0.f, a1 = 0.f, a2 = 0.f, a3 = 0.f;
  #pragma unroll 4
  for (int d4 = 0; d4 < DD / 4; ++d4) {
    const float4 w = W4[d4];
    const int d = d4 * 4;
    a0 = fmaf(w.x, rows[0][d], fmaf(w.y, rows[0][d+1], fmaf(w.z, rows[0][d+2], fmaf(w.w, rows[0][d+3], a0))));
    a1 = fmaf(w.x, rows[1][d], fmaf(w.y, rows[1][d+1], fmaf(w.z, rows[1][d+2], fmaf(w.w, rows[1][d+3], a1))));
    a2 = fmaf(w.x, rows[2][d], fmaf(w.y, rows[2][d+1], fmaf(w.z, rows[2][d+2], fmaf(w.w, rows[2][d+3], a2))));
    a3 = fmaf(w.x, rows[3][d], fmaf(w.y, rows[3][d+1], fmaf(w.z, rows[3][d+2], fmaf(w.w, rows[3][d+3], a3))));
  }
  float* orow = outp + (size_t)rb * HH + h;
  orow[0 * HH] = fmaf(a0, 32.0f, 72.0f);
  orow[1 * HH] = fmaf(a1, 32.0f, 72.0f);
  orow[2 * HH] = fmaf(a2, 32.0f, 72.0f);
  orow[3 * HH] = fmaf(a3, 32.0f, 72.0f);
}

// ---------------------------------------------------------------------------
// Kernel B: 32x32 output tile per block (grid 16x16x4), 256 threads,
// 4 outputs/thread.  tanh via LDS LUT; single accumulator (wd = w0-w1).
// ---------------------------------------------------------------------------
__global__ __launch_bounds__(256) void attn_kernel(
    const float* __restrict__ Qp, const float* __restrict__ Kp,
    const int* __restrict__ mask, const float* __restrict__ Wv,
    float* __restrict__ out) {
  __shared__ float4 QL[32][33];
  __shared__ float4 KL[32][33];
  __shared__ float4 wdL[32];      // Wv[0][h]-Wv[1][h]
  __shared__ float aT[NSEG];      // tanh(node_i)
  __shared__ float dT[NSEG];      // tanh(node_{i+1}) - tanh(node_i)

  const int bi = blockIdx.x, bj = blockIdx.y, b = blockIdx.z;
  const int i0 = bi * 32, j0 = bj * 32;

  // --- stage tiles + build LUT ---
  const float4* Q4 = reinterpret_cast<const float4*>(Qp) + ((size_t)b * LLEN + i0) * (HH / 4);
  const float4* K4 = reinterpret_cast<const float4*>(Kp) + ((size_t)b * LLEN + j0) * (HH / 4);
  for (int t = threadIdx.x; t < 32 * (HH / 4); t += 256) {
    QL[t >> 5][t & 31] = Q4[t];
    KL[t >> 5][t & 31] = K4[t];
  }
  if (threadIdx.x < 32) {
    const float4 w0 = reinterpret_cast<const float4*>(Wv)[threadIdx.x];
    const float4 w1 = reinterpret_cast<const float4*>(Wv)[32 + threadIdx.x];
    float4 wd; wd.x = w0.x - w1.x; wd.y = w0.y - w1.y;
    wd.z = w0.z - w1.z; wd.w = w0.w - w1.w;
    wdL[threadIdx.x] = wd;
  }
  for (int t = threadIdx.x; t < NSEG; t += 256) {
    const float x0 = (float)t * (1.0f / 32.0f) - 4.5f;
    const float v0 = tanhf(x0);
    const float v1 = tanhf(x0 + (1.0f / 32.0f));
    aT[t] = v0;
    dT[t] = v1 - v0;
  }
  __syncthreads();

  const int jj = threadIdx.x & 31;   // j within tile
  const int ib = threadIdx.x >> 5;   // i rows: ib, ib+8, ib+16, ib+24

  float acc[4] = {0.f, 0.f, 0.f, 0.f};

  // s = qv+kv is already 32*(q+k)+144 in [0,288]; clamp, split int/frac, interp
  auto lut = [&](float s) -> float {
    s = __builtin_amdgcn_fmed3f(s, 0.0f, 287.999f);
    const uint32_t ii = (uint32_t)s;
    const float t = s - (float)ii;
    return fmaf(dT[ii], t, aT[ii]);
  };

  #pragma unroll 4
  for (int h4 = 0; h4 < HH / 4; ++h4) {
    const float4 kv = KL[jj][h4];
    const float4 wd = wdL[h4];
    #pragma unroll
    for (int r = 0; r < 4; ++r) {
      const float4 qv = QL[ib + 8 * r][h4];
      const float t0 = lut(qv.x + kv.x);
      const float t1 = lut(qv.y + kv.y);
      const float t2 = lut(qv.z + kv.z);
      const float t3 = lut(qv.w + kv.w);
      acc[r] = fmaf(t0, wd.x, fmaf(t1, wd.y, fmaf(t2, wd.z, fmaf(t3, wd.w, acc[r]))));
    }
  }

  #pragma unroll
  for (int r = 0; r < 4; ++r) {
    const int i = i0 + ib + 8 * r;
    const int j = j0 + jj;
    const uint32_t idx = ((uint32_t)b * LLEN + i) * LLEN + j;
    float o = 1.0f;                      // mask==1: channel 1 at -1e6 -> exactly 1
    if (mask[idx] >= 2) {
      const float g0 = jax_gumbel(idx * 2u);
      const float g1 = jax_gumbel(idx * 2u + 1u);
      const float arg = (acc[r] + g0 - g1) * 100.0f;
      o = 1.0f / (1.0f + __expf(-arg));
    }
    out[idx] = o;
  }
}

extern "C" void kernel_launch(void* const* d_in, const int* in_sizes, int n_in,
                              void* d_out, int out_size, void* d_ws, size_t ws_size,
                              hipStream_t stream) {
  const float* queries = (const float*)d_in[0];
  const float* keys    = (const float*)d_in[1];
  const int*   mask    = (const int*)d_in[2];
  const float* Wq      = (const float*)d_in[3];
  const float* Wk      = (const float*)d_in[4];
  const float* Wv      = (const float*)d_in[5];
  float* out = (float*)d_out;

  float* Qp = (float*)d_ws;
  float* Kp = Qp + (size_t)BB * LLEN * HH;

  proj_kernel<<<dim3(2 * (BB * LLEN / 4)), dim3(128), 0, stream>>>(
      queries, keys, Wq, Wk, Qp, Kp);
  attn_kernel<<<dim3(LLEN / 32, LLEN / 32, BB), dim3(256), 0, stream>>>(
      Qp, Kp, mask, Wv, out);
}

// Round 5
// 56.748 us; speedup vs baseline: 1.7557x; 1.3247x over previous
//
#include <hip/hip_runtime.h>
#include <stdint.h>

// ---------------------------------------------------------------------------
// AdditiveAttention (Bahdanau) + gumbel-softmax(tau=0.01), channel 0.
//
// out[b,i,j] = (mask==1) ? 1.0
//            : sigmoid( (d + g0 - g1) * 100 ),  d = sum_h tanh(q+k)*(w0-w1)
//
// g = jax.random.gumbel(key(42)) bit-exact (threefry-2x32, partitionable,
// o0^o1) — verified passing R3/R4.
//
// tanh computed arithmetically (no LDS LUT — R4 showed 1.3e7 bank conflicts):
//   tanh(x) = 1 - 2*rcp(exp2(c*x) + 1),  c = 2*log2(e)
// with c pre-folded into the projections. Inner site = add, v_exp, add,
// v_rcp, fma (zero inner-loop LDS beyond conflict-free float4 tile reads).
// Channel fold: d = Swd - 2 * sum_h wd_h * r_h,  Swd = sum_h wd_h.
// ---------------------------------------------------------------------------

#define BB 4
#define LLEN 512
#define DD 256
#define HH 128

#define TWO_LOG2E 2.8853900817779268f   // 2*log2(e)
#define LOG2E_100 144.26950408889634f   // 100*log2(e)

__device__ __forceinline__ uint32_t rotl32(uint32_t v, int r) {
  return (v << r) | (v >> (32 - r));
}

// Threefry-2x32, key = (0, 42)
__device__ __forceinline__ void tf2x32(uint32_t x0, uint32_t x1,
                                       uint32_t& o0, uint32_t& o1) {
  const uint32_t k0 = 0u;
  const uint32_t k1 = 42u;
  const uint32_t k2 = 0x1BD11BDAu ^ k0 ^ k1;

  x0 += k0; x1 += k1;
#define TFR(r) { x0 += x1; x1 = rotl32(x1, (r)); x1 ^= x0; }
  TFR(13) TFR(15) TFR(26) TFR(6)
  x0 += k1; x1 += k2 + 1u;
  TFR(17) TFR(29) TFR(16) TFR(24)
  x0 += k2; x1 += k0 + 2u;
  TFR(13) TFR(15) TFR(26) TFR(6)
  x0 += k0; x1 += k1 + 3u;
  TFR(17) TFR(29) TFR(16) TFR(24)
  x0 += k1; x1 += k2 + 4u;
  TFR(13) TFR(15) TFR(26) TFR(6)
  x0 += k2; x1 += k0 + 5u;
#undef TFR
  o0 = x0; o1 = x1;
}

// jax partitionable random_bits: counter u64 = flat -> block (0, flat), o0^o1
// u = max(tiny, ((bits>>9)|0x3f800000) - 1); g = -log(-log(u)).
__device__ __forceinline__ float jax_gumbel(uint32_t flat) {
  uint32_t o0, o1;
  tf2x32(0u, flat, o0, o1);
  const uint32_t bits = o0 ^ o1;
  const float f = __uint_as_float((bits >> 9) | 0x3F800000u) - 1.0f;
  const float u = fmaxf(f, 1.17549435e-38f);
  const float L = -__logf(u);
  return -__logf(L);
}

// ---------------------------------------------------------------------------
// Kernel A: projections, pre-scaled: out = (2*log2e)*(in.W^T).
// blocks 0..511 -> Q rows, 512..1023 -> K rows; 4 rows/block, thread = h.
// ---------------------------------------------------------------------------
__global__ __launch_bounds__(128) void proj_kernel(
    const float* __restrict__ queries, const float* __restrict__ keys,
    const float* __restrict__ Wq, const float* __restrict__ Wk,
    float* __restrict__ Qp, float* __restrict__ Kp) {
  const int blk = blockIdx.x;
  const bool isK = blk >= (BB * LLEN / 4);
  const int rb = (isK ? blk - (BB * LLEN / 4) : blk) * 4;
  const float* __restrict__ in  = isK ? keys : queries;
  const float* __restrict__ W   = isK ? Wk : Wq;
  float* __restrict__ outp      = isK ? Kp : Qp;

  __shared__ float rows[4][DD];
  const float4* in4 = reinterpret_cast<const float4*>(in + (size_t)rb * DD);
  float4* rows4 = reinterpret_cast<float4*>(&rows[0][0]);
  for (int t = threadIdx.x; t < 4 * DD / 4; t += 128) rows4[t] = in4[t];
  __syncthreads();

  const int h = threadIdx.x;
  const float4* W4 = reinterpret_cast<const float4*>(W + (size_t)h * DD);
  float a0 = 0.f, a1 = 0.f, a2 = 0.f, a3 = 0.f;
  #pragma unroll 4
  for (int d4 = 0; d4 < DD / 4; ++d4) {
    const float4 w = W4[d4];
    const int d = d4 * 4;
    a0 = fmaf(w.x, rows[0][d], fmaf(w.y, rows[0][d+1], fmaf(w.z, rows[0][d+2], fmaf(w.w, rows[0][d+3], a0))));
    a1 = fmaf(w.x, rows[1][d], fmaf(w.y, rows[1][d+1], fmaf(w.z, rows[1][d+2], fmaf(w.w, rows[1][d+3], a1))));
    a2 = fmaf(w.x, rows[2][d], fmaf(w.y, rows[2][d+1], fmaf(w.z, rows[2][d+2], fmaf(w.w, rows[2][d+3], a2))));
    a3 = fmaf(w.x, rows[3][d], fmaf(w.y, rows[3][d+1], fmaf(w.z, rows[3][d+2], fmaf(w.w, rows[3][d+3], a3))));
  }
  float* orow = outp + (size_t)rb * HH + h;
  orow[0 * HH] = a0 * TWO_LOG2E;
  orow[1 * HH] = a1 * TWO_LOG2E;
  orow[2 * HH] = a2 * TWO_LOG2E;
  orow[3 * HH] = a3 * TWO_LOG2E;
}

// ---------------------------------------------------------------------------
// Kernel B: 32x32 output tile per block (grid 16x16x4), 256 threads,
// 4 outputs/thread.  tanh via v_exp + v_rcp, zero inner-loop LDS scatter.
// ---------------------------------------------------------------------------
__global__ __launch_bounds__(256) void attn_kernel(
    const float* __restrict__ Qp, const float* __restrict__ Kp,
    const int* __restrict__ mask, const float* __restrict__ Wv,
    float* __restrict__ out) {
  __shared__ float4 QL[32][33];
  __shared__ float4 KL[32][33];
  __shared__ float4 wdL[32];      // Wv[0][h]-Wv[1][h]

  const int bi = blockIdx.x, bj = blockIdx.y, b = blockIdx.z;
  const int i0 = bi * 32, j0 = bj * 32;

  const float4* Q4 = reinterpret_cast<const float4*>(Qp) + ((size_t)b * LLEN + i0) * (HH / 4);
  const float4* K4 = reinterpret_cast<const float4*>(Kp) + ((size_t)b * LLEN + j0) * (HH / 4);
  for (int t = threadIdx.x; t < 32 * (HH / 4); t += 256) {
    QL[t >> 5][t & 31] = Q4[t];
    KL[t >> 5][t & 31] = K4[t];
  }
  if (threadIdx.x < 32) {
    const float4 w0 = reinterpret_cast<const float4*>(Wv)[threadIdx.x];
    const float4 w1 = reinterpret_cast<const float4*>(Wv)[32 + threadIdx.x];
    float4 wd; wd.x = w0.x - w1.x; wd.y = w0.y - w1.y;
    wd.z = w0.z - w1.z; wd.w = w0.w - w1.w;
    wdL[threadIdx.x] = wd;
  }
  __syncthreads();

  const int jj = threadIdx.x & 31;   // j within tile
  const int ib = threadIdx.x >> 5;   // i rows: ib, ib+8, ib+16, ib+24

  // prefetch mask values (hide global latency under the main loop)
  int mreg[4];
  uint32_t idxr[4];
  #pragma unroll
  for (int r = 0; r < 4; ++r) {
    const int i = i0 + ib + 8 * r;
    idxr[r] = ((uint32_t)b * LLEN + i) * LLEN + (j0 + jj);
    mreg[r] = mask[idxr[r]];
  }

  // Swd = sum_h wd_h  (broadcast LDS reads — conflict-free)
  float Swd = 0.f;
  #pragma unroll
  for (int t = 0; t < 32; ++t) {
    const float4 wd = wdL[t];
    Swd += (wd.x + wd.y) + (wd.z + wd.w);
  }

  float acc[4] = {0.f, 0.f, 0.f, 0.f};   // sum_h wd_h * rcp(exp2(s)+1)

  #pragma unroll 4
  for (int h4 = 0; h4 < HH / 4; ++h4) {
    const float4 kv = KL[jj][h4];
    const float4 wd = wdL[h4];
    #pragma unroll
    for (int r = 0; r < 4; ++r) {
      const float4 qv = QL[ib + 8 * r][h4];
      const float r0 = __builtin_amdgcn_rcpf(__builtin_amdgcn_exp2f(qv.x + kv.x) + 1.0f);
      const float r1 = __builtin_amdgcn_rcpf(__builtin_amdgcn_exp2f(qv.y + kv.y) + 1.0f);
      const float r2 = __builtin_amdgcn_rcpf(__builtin_amdgcn_exp2f(qv.z + kv.z) + 1.0f);
      const float r3 = __builtin_amdgcn_rcpf(__builtin_amdgcn_exp2f(qv.w + kv.w) + 1.0f);
      acc[r] = fmaf(r0, wd.x, fmaf(r1, wd.y, fmaf(r2, wd.z, fmaf(r3, wd.w, acc[r]))));
    }
  }

  #pragma unroll
  for (int r = 0; r < 4; ++r) {
    float o = 1.0f;                      // mask==1: channel 1 at -1e6 -> exactly 1
    if (mreg[r] >= 2) {
      const float d = fmaf(-2.0f, acc[r], Swd);     // sum wd * tanh
      const float g0 = jax_gumbel(idxr[r] * 2u);
      const float g1 = jax_gumbel(idxr[r] * 2u + 1u);
      const float t = (d + g0 - g1) * LOG2E_100;    // arg/tau * log2e
      o = __builtin_amdgcn_rcpf(1.0f + __builtin_amdgcn_exp2f(-t));
    }
    out[idxr[r]] = o;
  }
}

extern "C" void kernel_launch(void* const* d_in, const int* in_sizes, int n_in,
                              void* d_out, int out_size, void* d_ws, size_t ws_size,
                              hipStream_t stream) {
  const float* queries = (const float*)d_in[0];
  const float* keys    = (const float*)d_in[1];
  const int*   mask    = (const int*)d_in[2];
  const float* Wq      = (const float*)d_in[3];
  const float* Wk      = (const float*)d_in[4];
  const float* Wv      = (const float*)d_in[5];
  float* out = (float*)d_out;

  float* Qp = (float*)d_ws;
  float* Kp = Qp + (size_t)BB * LLEN * HH;

  proj_kernel<<<dim3(2 * (BB * LLEN / 4)), dim3(128), 0, stream>>>(
      queries, keys, Wq, Wk, Qp, Kp);
  attn_kernel<<<dim3(LLEN / 32, LLEN / 32, BB), dim3(256), 0, stream>>>(
      Qp, Kp, mask, Wv, out);
}

// Round 6
// 56.302 us; speedup vs baseline: 1.7696x; 1.0079x over previous
//
#include <hip/hip_runtime.h>
#include <stdint.h>

// ---------------------------------------------------------------------------
// AdditiveAttention (Bahdanau) + gumbel-softmax(tau=0.01), channel 0.
//
// out[b,i,j] = (mask==1) ? 1.0
//            : sigmoid( (d + g0 - g1) * 100 ),  d = sum_h tanh(q+k)*(w0-w1)
//
// g = jax.random.gumbel(key(42)) bit-exact (threefry-2x32, partitionable,
// o0^o1) — verified passing R3-R5.
//
// R6: tanh ADDITION FORMULA — tanh(q+k) = (tq+tk)/(1+tq*tk) with tq,tk
// precomputed by the proj kernel. Inner site = add, fma, v_rcp, mul, fma:
// 4 full-rate + 1 trans (R5 was 3+2trans), and 16 INDEPENDENT accumulators
// acc[r][c] so no nested-fma serial tail (R5 was latency-stalled at
// VALUBusy=58%). Proj kernel: 8 Q-rows + 8 K-rows per block share one W
// pass (L2 traffic 131MB -> 32MB).
// ---------------------------------------------------------------------------

#define BB 4
#define LLEN 512
#define DD 256
#define HH 128

#define LOG2E_100 144.26950408889634f   // 100*log2(e)

__device__ __forceinline__ uint32_t rotl32(uint32_t v, int r) {
  return (v << r) | (v >> (32 - r));
}

// Threefry-2x32, key = (0, 42)
__device__ __forceinline__ void tf2x32(uint32_t x0, uint32_t x1,
                                       uint32_t& o0, uint32_t& o1) {
  const uint32_t k0 = 0u;
  const uint32_t k1 = 42u;
  const uint32_t k2 = 0x1BD11BDAu ^ k0 ^ k1;

  x0 += k0; x1 += k1;
#define TFR(r) { x0 += x1; x1 = rotl32(x1, (r)); x1 ^= x0; }
  TFR(13) TFR(15) TFR(26) TFR(6)
  x0 += k1; x1 += k2 + 1u;
  TFR(17) TFR(29) TFR(16) TFR(24)
  x0 += k2; x1 += k0 + 2u;
  TFR(13) TFR(15) TFR(26) TFR(6)
  x0 += k0; x1 += k1 + 3u;
  TFR(17) TFR(29) TFR(16) TFR(24)
  x0 += k1; x1 += k2 + 4u;
  TFR(13) TFR(15) TFR(26) TFR(6)
  x0 += k2; x1 += k0 + 5u;
#undef TFR
  o0 = x0; o1 = x1;
}

// jax partitionable random_bits: counter u64 = flat -> block (0, flat), o0^o1
// u = max(tiny, ((bits>>9)|0x3f800000) - 1); g = -log(-log(u)).
__device__ __forceinline__ float jax_gumbel(uint32_t flat) {
  uint32_t o0, o1;
  tf2x32(0u, flat, o0, o1);
  const uint32_t bits = o0 ^ o1;
  const float f = __uint_as_float((bits >> 9) | 0x3F800000u) - 1.0f;
  const float u = fmaxf(f, 1.17549435e-38f);
  const float L = -__logf(u);
  return -__logf(L);
}

// ---------------------------------------------------------------------------
// Kernel A: projections -> tq = tanh(q.Wq^T), tk = tanh(k.Wk^T).
// Each block: rows [rb, rb+8) of BOTH Q and K (shares the W pass).
// 256 threads: side = tid>>7 (0=Q, 1=K), h = tid&127.
// ---------------------------------------------------------------------------
__global__ __launch_bounds__(256) void proj_kernel(
    const float* __restrict__ queries, const float* __restrict__ keys,
    const float* __restrict__ Wq, const float* __restrict__ Wk,
    float* __restrict__ Qp, float* __restrict__ Kp) {
  const int rb = blockIdx.x * 8;   // rows rb..rb+7 (of 2048) on each side

  __shared__ float rows[2][8][DD];
  const int side_sz = 8 * DD / 4;  // 512 float4 per side
  for (int t = threadIdx.x; t < 2 * side_sz; t += 256) {
    const int s = t / side_sz;
    const int o = t - s * side_sz;
    const float4 v = reinterpret_cast<const float4*>(s ? keys : queries)
                         [(size_t)rb * (DD / 4) + o];
    reinterpret_cast<float4*>(&rows[s][0][0])[o] = v;
  }
  __syncthreads();

  const int h = threadIdx.x & 127;
  const int side = threadIdx.x >> 7;
  const float* __restrict__ W = side ? Wk : Wq;
  float* __restrict__ outp = side ? Kp : Qp;

  const float4* W4 = reinterpret_cast<const float4*>(W + (size_t)h * DD);
  float a[8] = {0.f, 0.f, 0.f, 0.f, 0.f, 0.f, 0.f, 0.f};
  for (int d4 = 0; d4 < DD / 4; ++d4) {
    const float4 w = W4[d4];
    const int d = d4 * 4;
    #pragma unroll
    for (int rr = 0; rr < 8; ++rr) {
      const float* rp = &rows[side][rr][d];   // wave-uniform addr: broadcast
      a[rr] = fmaf(w.x, rp[0], fmaf(w.y, rp[1], fmaf(w.z, rp[2], fmaf(w.w, rp[3], a[rr]))));
    }
  }
  #pragma unroll
  for (int rr = 0; rr < 8; ++rr)
    outp[(size_t)(rb + rr) * HH + h] = tanhf(a[rr]);
}

// ---------------------------------------------------------------------------
// Kernel B: 32x32 output tile per block (grid 16x16x4), 256 threads,
// 4 outputs/thread.  tanh via addition formula; 16 independent accumulators.
// ---------------------------------------------------------------------------
__global__ __launch_bounds__(256) void attn_kernel(
    const float* __restrict__ Qp, const float* __restrict__ Kp,
    const int* __restrict__ mask, const float* __restrict__ Wv,
    float* __restrict__ out) {
  __shared__ float4 QL[32][33];   // tq tile
  __shared__ float4 KL[32][33];   // tk tile
  __shared__ float4 wdL[32];      // Wv[0][h]-Wv[1][h]

  const int bi = blockIdx.x, bj = blockIdx.y, b = blockIdx.z;
  const int i0 = bi * 32, j0 = bj * 32;

  const float4* Q4 = reinterpret_cast<const float4*>(Qp) + ((size_t)b * LLEN + i0) * (HH / 4);
  const float4* K4 = reinterpret_cast<const float4*>(Kp) + ((size_t)b * LLEN + j0) * (HH / 4);
  for (int t = threadIdx.x; t < 32 * (HH / 4); t += 256) {
    QL[t >> 5][t & 31] = Q4[t];
    KL[t >> 5][t & 31] = K4[t];
  }
  if (threadIdx.x < 32) {
    const float4 w0 = reinterpret_cast<const float4*>(Wv)[threadIdx.x];
    const float4 w1 = reinterpret_cast<const float4*>(Wv)[32 + threadIdx.x];
    float4 wd; wd.x = w0.x - w1.x; wd.y = w0.y - w1.y;
    wd.z = w0.z - w1.z; wd.w = w0.w - w1.w;
    wdL[threadIdx.x] = wd;
  }
  __syncthreads();

  const int jj = threadIdx.x & 31;   // j within tile
  const int ib = threadIdx.x >> 5;   // i rows: ib, ib+8, ib+16, ib+24

  // prefetch mask values (hide global latency under the main loop)
  int mreg[4];
  uint32_t idxr[4];
  #pragma unroll
  for (int r = 0; r < 4; ++r) {
    const int i = i0 + ib + 8 * r;
    idxr[r] = ((uint32_t)b * LLEN + i) * LLEN + (j0 + jj);
    mreg[r] = mask[idxr[r]];
  }

  // 16 independent accumulators: acc[r][c] += wd_c * tanh(q+k)
  float acc[4][4];
  #pragma unroll
  for (int r = 0; r < 4; ++r)
    #pragma unroll
    for (int c = 0; c < 4; ++c) acc[r][c] = 0.f;

  #pragma unroll 4
  for (int h4 = 0; h4 < HH / 4; ++h4) {
    const float4 kv = KL[jj][h4];
    const float4 wd = wdL[h4];
    #pragma unroll
    for (int r = 0; r < 4; ++r) {
      const float4 qv = QL[ib + 8 * r][h4];
      // tanh(q+k) = (tq+tk) * rcp(1 + tq*tk)
      const float s0 = qv.x + kv.x, d0 = fmaf(qv.x, kv.x, 1.0f);
      const float s1 = qv.y + kv.y, d1 = fmaf(qv.y, kv.y, 1.0f);
      const float s2 = qv.z + kv.z, d2 = fmaf(qv.z, kv.z, 1.0f);
      const float s3 = qv.w + kv.w, d3 = fmaf(qv.w, kv.w, 1.0f);
      const float r0 = __builtin_amdgcn_rcpf(d0);
      const float r1 = __builtin_amdgcn_rcpf(d1);
      const float r2 = __builtin_amdgcn_rcpf(d2);
      const float r3 = __builtin_amdgcn_rcpf(d3);
      acc[r][0] = fmaf(wd.x, s0 * r0, acc[r][0]);
      acc[r][1] = fmaf(wd.y, s1 * r1, acc[r][1]);
      acc[r][2] = fmaf(wd.z, s2 * r2, acc[r][2]);
      acc[r][3] = fmaf(wd.w, s3 * r3, acc[r][3]);
    }
  }

  #pragma unroll
  for (int r = 0; r < 4; ++r) {
    float o = 1.0f;                      // mask==1: channel 1 at -1e6 -> exactly 1
    if (mreg[r] >= 2) {
      const float d = (acc[r][0] + acc[r][1]) + (acc[r][2] + acc[r][3]);
      const float g0 = jax_gumbel(idxr[r] * 2u);
      const float g1 = jax_gumbel(idxr[r] * 2u + 1u);
      const float t = (d + g0 - g1) * LOG2E_100;    // arg/tau * log2e
      o = __builtin_amdgcn_rcpf(1.0f + __builtin_amdgcn_exp2f(-t));
    }
    out[idxr[r]] = o;
  }
}

extern "C" void kernel_launch(void* const* d_in, const int* in_sizes, int n_in,
                              void* d_out, int out_size, void* d_ws, size_t ws_size,
                              hipStream_t stream) {
  const float* queries = (const float*)d_in[0];
  const float* keys    = (const float*)d_in[1];
  const int*   mask    = (const int*)d_in[2];
  const float* Wq      = (const float*)d_in[3];
  const float* Wk      = (const float*)d_in[4];
  const float* Wv      = (const float*)d_in[5];
  float* out = (float*)d_out;

  float* Qp = (float*)d_ws;   // tq [2048][128]
  float* Kp = Qp + (size_t)BB * LLEN * HH;  // tk [2048][128]

  proj_kernel<<<dim3(BB * LLEN / 8), dim3(256), 0, stream>>>(
      queries, keys, Wq, Wk, Qp, Kp);
  attn_kernel<<<dim3(LLEN / 32, LLEN / 32, BB), dim3(256), 0, stream>>>(
      Qp, Kp, mask, Wv, out);
}